// Round 1
// baseline (1345.245 us; speedup 1.0000x reference)
//
#include <hip/hip_runtime.h>
#include <hip/hip_bf16.h>

#define H 192
#define HH (192*192)
#define NLAYER 13
#define LSTRIDE (2*HH)         // shorts per layer in fragment-ordered weight buffer
#define VB 128                 // vertices per spmm block (x 3 lanes = 384 threads)
#define GR 48                  // rows per gemm block (3 tiles of 16)

typedef unsigned short u16;
typedef unsigned int u32;

typedef __attribute__((ext_vector_type(8))) short short8;
typedef __attribute__((ext_vector_type(4))) float floatx4;

__device__ __forceinline__ u16 f2bf(float f) {
    u32 u = __float_as_uint(f);
    u32 r = (u + 0x7FFFu + ((u >> 16) & 1u)) >> 16;   // RNE
    return (u16)r;
}
__device__ __forceinline__ float bf2f(u16 h) {
    return __uint_as_float(((u32)h) << 16);
}

// ---------------- CSR construction (scan-free, single range) ----------------
// Col-slab SpMM makes each XCD's S working set 1.2MB (structurally L2-resident),
// so src-range ordering within rows is no longer needed.

__global__ void hist_kernel(const int* __restrict__ dst, int* __restrict__ counts, int E) {
    int e = blockIdx.x * blockDim.x + threadIdx.x;
    if (e < E) atomicAdd(&counts[dst[e]], 1);
}

__global__ void alloc_kernel(const int* __restrict__ counts, int* __restrict__ rbeg,
                             int* __restrict__ rcnt, int* __restrict__ cursor,
                             int* __restrict__ total, int Nv) {
    int v = blockIdx.x * blockDim.x + threadIdx.x;
    if (v >= Nv) return;
    int cnt = counts[v];
    int base = atomicAdd(total, cnt);    // uniform-address: wave-coalesced by compiler
    rbeg[v] = base;
    rcnt[v] = cnt;
    cursor[v] = base;
}

__global__ void scatter_kernel(const int* __restrict__ src, const int* __restrict__ dst,
                               const float* __restrict__ w, int* __restrict__ cursor,
                               int2* __restrict__ ce, int E) {
    int e = blockIdx.x * blockDim.x + threadIdx.x;
    if (e < E) {
        int p = atomicAdd(&cursor[dst[e]], 1);
        int2 pk; pk.x = src[e]; pk.y = __float_as_int(w[e]);
        ce[p] = pk;
    }
}

// ---------------- Weight prep: fragment-ordered ----------------
// Wf[l][group][lane][j], group = ks*12 + nt. lane = quad*16 + col encodes
// B[n=nt*16+col][k=ks*32+quad*8+j]; hi at +0, lo at +512 within the group.

__global__ void wprep_kernel(const float* __restrict__ W, u16* __restrict__ Wf, int total) {
    int idx = blockIdx.x * blockDim.x + threadIdx.x;
    if (idx >= total) return;
    int l = idx / HH;
    int rem = idx - l * HH;
    int k = rem / H;
    int n = rem - k * H;
    float v = W[idx];
    u16 hi = f2bf(v);
    u16 lo = f2bf(v - bf2f(hi));
    int ks = k >> 5, quad = (k >> 3) & 3, j = k & 7;
    int nt = n >> 4, col = n & 15;
    int lane = quad * 16 + col;
    size_t base = (size_t)l * LSTRIDE + (size_t)(ks * 12 + nt) * 1024 + lane * 8 + j;
    Wf[base] = hi;
    Wf[base + 512] = lo;
}

// ---------------- features fp32 -> bf16 ----------------

__global__ void conv_kernel(const float* __restrict__ in, u16* __restrict__ out, int total4) {
    int idx = blockIdx.x * blockDim.x + threadIdx.x;
    if (idx >= total4) return;
    float4 v = ((const float4*)in)[idx];
    ushort4 p;
    p.x = f2bf(v.x); p.y = f2bf(v.y); p.z = f2bf(v.z); p.w = f2bf(v.w);
    ((ushort4*)out)[idx] = p;
}

// ---------------- common fma helper ----------------

__device__ __forceinline__ void fma8(float* acc, uint4 q, float w) {
    u32 u[4] = {q.x, q.y, q.z, q.w};
    #pragma unroll
    for (int i = 0; i < 4; i++) {
        float lo = __uint_as_float(u[i] << 16);
        float hi = __uint_as_float(u[i] & 0xFFFF0000u);
        acc[2*i]     += w * lo;
        acc[2*i + 1] += w * hi;
    }
}

// ---------------- Col-slab SpMM: agg = adj @ S, XCD-affine slabs ------------
// Block = 384 threads = 128 vertices x 3 lanes; each block covers one 24-col
// slab (48B) of its vertices. slab = blockIdx & 7 -> round-robin dispatch pins
// slab s to XCD s, so the gather working set per XCD is 25000*48B = 1.2MB:
// structurally resident in the 4MB XCD L2. S is fetched from HBM once total.

__global__ __launch_bounds__(384) void spmm_slab(
    const u16* __restrict__ S, const int* __restrict__ rbeg, const int* __restrict__ rcnt,
    const int2* __restrict__ ce, u16* __restrict__ agg, int M)
{
    int slab = blockIdx.x & 7;
    int vb   = blockIdx.x >> 3;
    int tid  = threadIdx.x;
    int vg = tid / 3;                    // vertex 0..127 within block
    int l  = tid - vg * 3;               // lane in vertex, owns 8 cols
    int v = vb * VB + vg;
    if (v >= M) return;

    const u16* Sc = S + slab * 24 + l * 8;
    int beg = rbeg[v], cnt = rcnt[v];
    const int2* cep = ce + beg;
    float acc[8] = {};
    int e = 0;
    for (; e + 3 < cnt; e += 4) {
        int2 p0 = cep[e], p1 = cep[e + 1], p2 = cep[e + 2], p3 = cep[e + 3];
        uint4 q0 = *(const uint4*)(Sc + (size_t)p0.x * H);
        uint4 q1 = *(const uint4*)(Sc + (size_t)p1.x * H);
        uint4 q2 = *(const uint4*)(Sc + (size_t)p2.x * H);
        uint4 q3 = *(const uint4*)(Sc + (size_t)p3.x * H);
        fma8(acc, q0, __int_as_float(p0.y));
        fma8(acc, q1, __int_as_float(p1.y));
        fma8(acc, q2, __int_as_float(p2.y));
        fma8(acc, q3, __int_as_float(p3.y));
    }
    for (; e < cnt; e++) {
        int2 p0 = cep[e];
        uint4 q0 = *(const uint4*)(Sc + (size_t)p0.x * H);
        fma8(acc, q0, __int_as_float(p0.y));
    }

    uint4 p;
    p.x = (u32)f2bf(acc[0]) | ((u32)f2bf(acc[1]) << 16);
    p.y = (u32)f2bf(acc[2]) | ((u32)f2bf(acc[3]) << 16);
    p.z = (u32)f2bf(acc[4]) | ((u32)f2bf(acc[5]) << 16);
    p.w = (u32)f2bf(acc[6]) | ((u32)f2bf(acc[7]) << 16);
    *(uint4*)&agg[(size_t)v * H + slab * 24 + l * 8] = p;
}

// ---------------- GEMM + epilogue: out = epi(agg @ W + b) -------------------
// Block = 384 threads = 6 waves; wave w owns n-tiles {w, w+6}. B-frags (hi+lo)
// are loaded ONCE into registers (96 VGPR) and reused across GR/16 = 3 row
// tiles -> Wf L2 traffic cut 3x vs 16-row blocks. A-frags read directly from
// global agg (no LDS, no syncthreads).
// mode 0: out_bf = bf16(relu(C+b)); mode 1: f=(resid+relu(C+b))*0.5 -> out_bf;
// mode 2: mode 1 + out_f = f (fp32).

__global__ __launch_bounds__(384) void gemm_layer(
    const u16* __restrict__ A, const u16* __restrict__ Wf, const float* __restrict__ bias,
    u16* __restrict__ out_bf, float* __restrict__ out_f, const u16* __restrict__ resid_bf,
    int mode, int M)
{
    int tid = threadIdx.x;
    int wave = tid >> 6, lane = tid & 63;
    int col = lane & 15, quad = lane >> 4;
    int nt0 = wave, nt1 = wave + 6;

    short8 bh0[6], bl0[6], bh1[6], bl1[6];
    #pragma unroll
    for (int ks = 0; ks < 6; ks++) {
        const u16* g0 = Wf + (size_t)(ks * 12 + nt0) * 1024 + lane * 8;
        const u16* g1 = Wf + (size_t)(ks * 12 + nt1) * 1024 + lane * 8;
        bh0[ks] = *(const short8*)g0;
        bl0[ks] = *(const short8*)(g0 + 512);
        bh1[ks] = *(const short8*)g1;
        bl1[ks] = *(const short8*)(g1 + 512);
    }

    int rm0 = blockIdx.x * GR;
    #pragma unroll
    for (int t = 0; t < GR / 16; t++) {
        int rm = rm0 + t * 16;
        if (rm >= M) break;

        int arow = rm + col;
        if (arow >= M) arow = M - 1;     // clamp: garbage rows never stored
        const u16* Ar = A + (size_t)arow * H + quad * 8;
        short8 a[6];
        #pragma unroll
        for (int ks = 0; ks < 6; ks++) a[ks] = *(const short8*)(Ar + ks * 32);

        floatx4 c0 = {0.f, 0.f, 0.f, 0.f}, c1 = {0.f, 0.f, 0.f, 0.f};
        #pragma unroll
        for (int ks = 0; ks < 6; ks++) {
            c0 = __builtin_amdgcn_mfma_f32_16x16x32_bf16(a[ks], bh0[ks], c0, 0, 0, 0);
            c0 = __builtin_amdgcn_mfma_f32_16x16x32_bf16(a[ks], bl0[ks], c0, 0, 0, 0);
            c1 = __builtin_amdgcn_mfma_f32_16x16x32_bf16(a[ks], bh1[ks], c1, 0, 0, 0);
            c1 = __builtin_amdgcn_mfma_f32_16x16x32_bf16(a[ks], bl1[ks], c1, 0, 0, 0);
        }

        // C layout: col=lane&15, row=quad*4+r
        #pragma unroll
        for (int half = 0; half < 2; half++) {
            int nt = half ? nt1 : nt0;
            floatx4 cc = half ? c1 : c0;
            int n = nt * 16 + col;
            float b = bias[n];
            #pragma unroll
            for (int r = 0; r < 4; r++) {
                int row = rm + quad * 4 + r;
                if (row < M) {
                    float z = fmaxf(cc[r] + b, 0.f);
                    size_t o = (size_t)row * H + n;
                    if (mode >= 1) {
                        float f = (bf2f(resid_bf[o]) + z) * 0.5f;
                        out_bf[o] = f2bf(f);
                        if (mode == 2) out_f[o] = f;
                    } else {
                        out_bf[o] = f2bf(z);
                    }
                }
            }
        }
    }
}

// ---------------- Output head: coords = sup @ W_out + b_out ----------------

__global__ void head_kernel(const u16* __restrict__ A, const float* __restrict__ W,
                            const float* __restrict__ b, float* __restrict__ coords, int M) {
    int row = blockIdx.x * blockDim.x + threadIdx.x;
    if (row >= M) return;
    float a0 = b[0], a1 = b[1], a2 = b[2];
    const u16* Ar = A + (size_t)row * H;
    #pragma unroll
    for (int k8 = 0; k8 < H / 8; k8++) {
        short8 v = *(const short8*)(Ar + k8 * 8);
        #pragma unroll
        for (int j = 0; j < 8; j++) {
            float x = bf2f((u16)v[j]);
            int k = k8 * 8 + j;
            a0 += x * W[k * 3 + 0];
            a1 += x * W[k * 3 + 1];
            a2 += x * W[k * 3 + 2];
        }
    }
    coords[row * 3 + 0] = a0;
    coords[row * 3 + 1] = a1;
    coords[row * 3 + 2] = a2;
}

// ---------------- Launch ----------------

extern "C" void kernel_launch(void* const* d_in, const int* in_sizes, int n_in,
                              void* d_out, int out_size, void* d_ws, size_t ws_size,
                              hipStream_t stream) {
    const float* features = (const float*)d_in[0];
    const int*   edge_src = (const int*)d_in[1];
    const int*   edge_dst = (const int*)d_in[2];
    const float* edge_w   = (const float*)d_in[3];
    const float* Ws       = (const float*)d_in[4];
    const float* bs       = (const float*)d_in[5];
    const float* W_out    = (const float*)d_in[6];
    const float* b_out    = (const float*)d_in[7];

    const int N = in_sizes[0] / H;
    const int E = in_sizes[1];

    float* coords = (float*)d_out;
    float* feats  = coords + (size_t)N * 3;   // fp32 final feats (written at gc13 only)

    char* wptr = (char*)d_ws;
    u16* fbf  = (u16*)wptr;   wptr += (size_t)N * H * sizeof(u16);  // bf16 features
    u16* xb   = (u16*)wptr;   wptr += (size_t)N * H * sizeof(u16);  // x buffer
    u16* fA   = (u16*)wptr;   wptr += (size_t)N * H * sizeof(u16);  // feats ping
    u16* fB   = (u16*)wptr;   wptr += (size_t)N * H * sizeof(u16);  // feats pong
    u16* agg  = (u16*)wptr;   wptr += (size_t)N * H * sizeof(u16);  // SpMM output
    u16* Wf   = (u16*)wptr;   wptr += (size_t)NLAYER * LSTRIDE * sizeof(u16);
    int* counts = (int*)wptr; wptr += (size_t)N * sizeof(int);      // N*4 is 16B-mult
    int* total  = (int*)wptr; wptr += 16;
    int* rbeg   = (int*)wptr; wptr += (size_t)N * sizeof(int);
    int* rcnt   = (int*)wptr; wptr += (size_t)N * sizeof(int);
    int* cursor = (int*)wptr; wptr += (size_t)N * sizeof(int);
    int2* ce    = (int2*)wptr; wptr += (size_t)E * sizeof(int2);

    // --- build CSR (dst-indexed, scan-free) ---
    hipMemsetAsync(counts, 0, (size_t)N * sizeof(int) + 16, stream);  // counts + total
    hist_kernel<<<(E + 255) / 256, 256, 0, stream>>>(edge_dst, counts, E);
    alloc_kernel<<<(N + 255) / 256, 256, 0, stream>>>(counts, rbeg, rcnt, cursor, total, N);
    scatter_kernel<<<(E + 255) / 256, 256, 0, stream>>>(edge_src, edge_dst, edge_w,
                                                        cursor, ce, E);

    // --- weight split + fragment reorder + feature conversion ---
    int wtotal = NLAYER * HH;
    wprep_kernel<<<(wtotal + 255) / 256, 256, 0, stream>>>(Ws, Wf, wtotal);
    int c4 = N * H / 4;
    conv_kernel<<<(c4 + 255) / 256, 256, 0, stream>>>(features, fbf, c4);

    int nvb = (N + VB - 1) / VB;
    int sg  = 8 * nvb;                   // 8 slabs x vertex-groups
    int gb  = (N + GR - 1) / GR;

    // L0: x0 = relu((adj@fbf) W0 + b0)
    spmm_slab<<<sg, 384, 0, stream>>>(fbf, rbeg, rcnt, ce, agg, N);
    gemm_layer<<<gb, 384, 0, stream>>>(agg, Wf, bs, xb, nullptr, nullptr, 0, N);
    // L1: fA = (fbf + relu((adj@xb) W1 + b1))/2
    spmm_slab<<<sg, 384, 0, stream>>>(xb, rbeg, rcnt, ce, agg, N);
    gemm_layer<<<gb, 384, 0, stream>>>(agg, Wf + (size_t)LSTRIDE, bs + H, fA,
                                       nullptr, fbf, 1, N);

    // blocks 2-6: ping-pong cur/nxt
    u16* cur = fA;
    u16* nxt = fB;
    for (int i = 2; i < 12; i += 2) {
        spmm_slab<<<sg, 384, 0, stream>>>(cur, rbeg, rcnt, ce, agg, N);
        gemm_layer<<<gb, 384, 0, stream>>>(agg, Wf + (size_t)i * LSTRIDE, bs + (size_t)i * H,
                                           xb, nullptr, nullptr, 0, N);
        spmm_slab<<<sg, 384, 0, stream>>>(xb, rbeg, rcnt, ce, agg, N);
        gemm_layer<<<gb, 384, 0, stream>>>(agg, Wf + (size_t)(i + 1) * LSTRIDE,
                                           bs + (size_t)(i + 1) * H, nxt, nullptr, cur, 1, N);
        u16* t = cur; cur = nxt; nxt = t;
    }

    // gc13: nxt = (cur + relu(...))/2, also fp32 feats to d_out
    spmm_slab<<<sg, 384, 0, stream>>>(cur, rbeg, rcnt, ce, agg, N);
    gemm_layer<<<gb, 384, 0, stream>>>(agg, Wf + 12 * (size_t)LSTRIDE, bs + 12 * H,
                                       nxt, feats, cur, 2, N);

    // head: coords = (adj@nxt) W_out + b_out
    spmm_slab<<<sg, 384, 0, stream>>>(nxt, rbeg, rcnt, ce, agg, N);
    head_kernel<<<(N + 255) / 256, 256, 0, stream>>>(agg, W_out, b_out, coords, N);
}

// Round 2
// 753.732 us; speedup vs baseline: 1.7848x; 1.7848x over previous
//
#include <hip/hip_runtime.h>
#include <hip/hip_bf16.h>

#define H 192
#define HH (192*192)
#define NLAYER 13
#define LSTRIDE (2*HH)         // shorts per layer in fragment-ordered weight buffer
#define ASTRIDE 200            // A-tile row stride in shorts (400B, 16B-aligned)
#define EMAX 64                // staged edges per vertex (LDS), tail from global

typedef unsigned short u16;
typedef unsigned int u32;

typedef __attribute__((ext_vector_type(8))) short short8;
typedef __attribute__((ext_vector_type(4))) float floatx4;

__device__ __forceinline__ u16 f2bf(float f) {
    u32 u = __float_as_uint(f);
    u32 r = (u + 0x7FFFu + ((u >> 16) & 1u)) >> 16;   // RNE
    return (u16)r;
}
__device__ __forceinline__ float bf2f(u16 h) {
    return __uint_as_float(((u32)h) << 16);
}

// ---------------- CSR construction (scan-free), src-range-sorted rows --------
// Edges within each dst row are bucketed by src range (3 ranges of ~N/3) so
// concurrently-running gather blocks sweep the same ~3.2MB of S rows.

__global__ void hist2_kernel(const int* __restrict__ src, const int* __restrict__ dst,
                             int* __restrict__ counts2, int E, int t1, int t2) {
    int e = blockIdx.x * blockDim.x + threadIdx.x;
    if (e < E) {
        int s = src[e];
        int r = (s >= t2) ? 2 : ((s >= t1) ? 1 : 0);
        atomicAdd(&counts2[dst[e] * 4 + r], 1);
    }
}

__global__ void alloc2_kernel(const int* __restrict__ counts2, int* __restrict__ rbeg,
                              int* __restrict__ rcnt, int* __restrict__ cursor,
                              int* __restrict__ total, int Nv) {
    int v = blockIdx.x * blockDim.x + threadIdx.x;
    if (v >= Nv) return;
    int c0 = counts2[v * 4 + 0];
    int c1 = counts2[v * 4 + 1];
    int c2 = counts2[v * 4 + 2];
    int tot = c0 + c1 + c2;
    int base = atomicAdd(total, tot);    // uniform-address: wave-coalesced by compiler
    rbeg[v] = base;
    rcnt[v] = tot;
    cursor[v * 4 + 0] = base;
    cursor[v * 4 + 1] = base + c0;
    cursor[v * 4 + 2] = base + c0 + c1;
}

__global__ void scatter2_kernel(const int* __restrict__ src, const int* __restrict__ dst,
                                const float* __restrict__ w, int* __restrict__ cursor,
                                int2* __restrict__ ce, int E, int t1, int t2) {
    int e = blockIdx.x * blockDim.x + threadIdx.x;
    if (e < E) {
        int s = src[e];
        int r = (s >= t2) ? 2 : ((s >= t1) ? 1 : 0);
        int p = atomicAdd(&cursor[dst[e] * 4 + r], 1);
        int2 pk; pk.x = s; pk.y = __float_as_int(w[e]);
        ce[p] = pk;
    }
}

// ---------------- Weight prep: fragment-ordered ----------------
// Wf[l][group][lane][j], group = ks*12 + nt. lane = quad*16 + col encodes
// B[n=nt*16+col][k=ks*32+quad*8+j]; hi at +0, lo at +512 within the group.

__global__ void wprep_kernel(const float* __restrict__ W, u16* __restrict__ Wf, int total) {
    int idx = blockIdx.x * blockDim.x + threadIdx.x;
    if (idx >= total) return;
    int l = idx / HH;
    int rem = idx - l * HH;
    int k = rem / H;
    int n = rem - k * H;
    float v = W[idx];
    u16 hi = f2bf(v);
    u16 lo = f2bf(v - bf2f(hi));
    int ks = k >> 5, quad = (k >> 3) & 3, j = k & 7;
    int nt = n >> 4, col = n & 15;
    int lane = quad * 16 + col;
    size_t base = (size_t)l * LSTRIDE + (size_t)(ks * 12 + nt) * 1024 + lane * 8 + j;
    Wf[base] = hi;
    Wf[base + 512] = lo;
}

// ---------------- features fp32 -> bf16 ----------------

__global__ void conv_kernel(const float* __restrict__ in, u16* __restrict__ out, int total4) {
    int idx = blockIdx.x * blockDim.x + threadIdx.x;
    if (idx >= total4) return;
    float4 v = ((const float4*)in)[idx];
    ushort4 p;
    p.x = f2bf(v.x); p.y = f2bf(v.y); p.z = f2bf(v.z); p.w = f2bf(v.w);
    ((ushort4*)out)[idx] = p;
}

// ---------------- common fma helper ----------------

__device__ __forceinline__ void fma8(float* acc, uint4 q, float w) {
    u32 u[4] = {q.x, q.y, q.z, q.w};
    #pragma unroll
    for (int i = 0; i < 4; i++) {
        float lo = __uint_as_float(u[i] << 16);
        float hi = __uint_as_float(u[i] & 0xFFFF0000u);
        acc[2*i]     += w * lo;
        acc[2*i + 1] += w * hi;
    }
}

// ---------------- Fused layer: agg = adj @ S ; out = epilogue(agg @ W + b) ---
// RACE RULE: S (gather input) must NEVER alias out_bf/out_f. resid_bf may
// alias S (read-only).
// Block = 384 threads = 16 dst vertices x 24 lanes.
// Phase 0: coalesced copy of each vertex's edge meta (<=EMAX) into LDS.
// Phase 1: lane owns 8 cols; meta from LDS (off the global-latency chain);
//          8 row-loads in flight per lane. Edges are src-range-sorted.
// Phase 2: 6 waves; wave w does n-tiles {w, w+6}; B-frags direct from
//          fragment-ordered Wf (lane-contiguous 16B, L2-hot); A via ds_read_b128.
// mode 0: out_bf = bf16(relu(C+b)); mode 1: f=(resid+relu(C+b))*0.5 -> out_bf;
// mode 2: mode 1 + out_f = f (fp32).

__global__ __launch_bounds__(384) void fused_layer(
    const u16* __restrict__ S, const int* __restrict__ rbeg, const int* __restrict__ rcnt,
    const int2* __restrict__ ce, const u16* __restrict__ Wf, const float* __restrict__ bias,
    u16* __restrict__ out_bf, float* __restrict__ out_f, const u16* __restrict__ resid_bf,
    int mode, int M)
{
    __shared__ u16 shA[16 * ASTRIDE];         // 6.4 KB A-tile
    __shared__ int2 sce[16][EMAX + 1];        // 8.3 KB edge meta (+1 pad: bank spread)
    int tid = threadIdx.x;
    int vg = tid / 24;                   // vertex 0..15
    int l  = tid - vg * 24;              // lane in vertex, owns cols l*8..l*8+7
    int v = blockIdx.x * 16 + vg;

    int beg = 0, cnt = 0, stg = 0;
    if (v < M) {
        beg = rbeg[v]; cnt = rcnt[v];
        stg = cnt < EMAX ? cnt : EMAX;
        // phase 0: coalesced meta copy (24 lanes stride the vertex's edge list)
        const int2* cep = ce + beg;
        for (int e = l; e < stg; e += 24) sce[vg][e] = cep[e];
    }
    __syncthreads();

    float acc1[8] = {};
    if (v < M) {
        const int2* cep = ce + beg;
        const u16* Sc = S + l * 8;
        const int2* sm = &sce[vg][0];
        int e = 0;
        for (; e + 7 < stg; e += 8) {
            int2 m0 = sm[e],     m1 = sm[e + 1], m2 = sm[e + 2], m3 = sm[e + 3];
            int2 m4 = sm[e + 4], m5 = sm[e + 5], m6 = sm[e + 6], m7 = sm[e + 7];
            uint4 q0 = *(const uint4*)(Sc + (size_t)m0.x * H);
            uint4 q1 = *(const uint4*)(Sc + (size_t)m1.x * H);
            uint4 q2 = *(const uint4*)(Sc + (size_t)m2.x * H);
            uint4 q3 = *(const uint4*)(Sc + (size_t)m3.x * H);
            uint4 q4 = *(const uint4*)(Sc + (size_t)m4.x * H);
            uint4 q5 = *(const uint4*)(Sc + (size_t)m5.x * H);
            uint4 q6 = *(const uint4*)(Sc + (size_t)m6.x * H);
            uint4 q7 = *(const uint4*)(Sc + (size_t)m7.x * H);
            fma8(acc1, q0, __int_as_float(m0.y));
            fma8(acc1, q1, __int_as_float(m1.y));
            fma8(acc1, q2, __int_as_float(m2.y));
            fma8(acc1, q3, __int_as_float(m3.y));
            fma8(acc1, q4, __int_as_float(m4.y));
            fma8(acc1, q5, __int_as_float(m5.y));
            fma8(acc1, q6, __int_as_float(m6.y));
            fma8(acc1, q7, __int_as_float(m7.y));
        }
        for (; e < stg; e++) {
            int2 m0 = sm[e];
            uint4 q0 = *(const uint4*)(Sc + (size_t)m0.x * H);
            fma8(acc1, q0, __int_as_float(m0.y));
        }
        for (; e < cnt; e++) {               // overflow tail (cnt > EMAX), from global
            int2 p0 = cep[e];
            uint4 q0 = *(const uint4*)(Sc + (size_t)p0.x * H);
            fma8(acc1, q0, __int_as_float(p0.y));
        }
    }
    {
        uint4 p;
        p.x = (u32)f2bf(acc1[0]) | ((u32)f2bf(acc1[1]) << 16);
        p.y = (u32)f2bf(acc1[2]) | ((u32)f2bf(acc1[3]) << 16);
        p.z = (u32)f2bf(acc1[4]) | ((u32)f2bf(acc1[5]) << 16);
        p.w = (u32)f2bf(acc1[6]) | ((u32)f2bf(acc1[7]) << 16);
        *(uint4*)&shA[vg * ASTRIDE + l * 8] = p;
    }
    __syncthreads();

    // ---- phase 2: MFMA (6 waves x 2 n-tiles) ----
    int wave = tid >> 6, lane = tid & 63;
    int col = lane & 15, quad = lane >> 4;

    short8 a[6];
    {
        const u16* Ar = &shA[col * ASTRIDE + quad * 8];
        #pragma unroll
        for (int ks = 0; ks < 6; ks++) a[ks] = *(const short8*)(Ar + ks * 32);
    }

    int nt0 = wave, nt1 = wave + 6;
    floatx4 c0 = {0.f, 0.f, 0.f, 0.f}, c1 = {0.f, 0.f, 0.f, 0.f};
    #pragma unroll
    for (int ks = 0; ks < 6; ks++) {
        const u16* g0 = Wf + (size_t)(ks * 12 + nt0) * 1024 + lane * 8;
        const u16* g1 = Wf + (size_t)(ks * 12 + nt1) * 1024 + lane * 8;
        short8 bh0 = *(const short8*)g0;
        short8 bl0 = *(const short8*)(g0 + 512);
        short8 bh1 = *(const short8*)g1;
        short8 bl1 = *(const short8*)(g1 + 512);
        c0 = __builtin_amdgcn_mfma_f32_16x16x32_bf16(a[ks], bh0, c0, 0, 0, 0);
        c0 = __builtin_amdgcn_mfma_f32_16x16x32_bf16(a[ks], bl0, c0, 0, 0, 0);
        c1 = __builtin_amdgcn_mfma_f32_16x16x32_bf16(a[ks], bh1, c1, 0, 0, 0);
        c1 = __builtin_amdgcn_mfma_f32_16x16x32_bf16(a[ks], bl1, c1, 0, 0, 0);
    }

    // ---- epilogue: C layout col=lane&15, row=quad*4+r ----
    int rm = blockIdx.x * 16;
    #pragma unroll
    for (int half = 0; half < 2; half++) {
        int nt = half ? nt1 : nt0;
        floatx4 cc = half ? c1 : c0;
        int n = nt * 16 + col;
        float b = bias[n];
        #pragma unroll
        for (int r = 0; r < 4; r++) {
            int row = rm + quad * 4 + r;
            if (row < M) {
                float z = fmaxf(cc[r] + b, 0.f);
                size_t o = (size_t)row * H + n;
                if (mode >= 1) {
                    float f = (bf2f(resid_bf[o]) + z) * 0.5f;
                    out_bf[o] = f2bf(f);
                    if (mode == 2) out_f[o] = f;
                } else {
                    out_bf[o] = f2bf(z);
                }
            }
        }
    }
}

// ---------------- head gather: sup = adj @ feats_bf ----------------

__global__ __launch_bounds__(192) void spmm_raw(
    const u16* __restrict__ S, const int* __restrict__ rbeg, const int* __restrict__ rcnt,
    const int2* __restrict__ ce, u16* __restrict__ out, int Nv)
{
    int tid = threadIdx.x;
    int g = tid / 24;
    int l = tid - g * 24;
    int v = blockIdx.x * 8 + g;
    if (v >= Nv) return;
    int beg = rbeg[v], cnt = rcnt[v];
    const int2* cep = ce + beg;
    const u16* Sc = S + l * 8;
    float acc[8] = {};
    int e = 0;
    for (; e + 3 < cnt; e += 4) {
        int2 p0 = cep[e], p1 = cep[e + 1], p2 = cep[e + 2], p3 = cep[e + 3];
        uint4 q0 = *(const uint4*)(Sc + (size_t)p0.x * H);
        uint4 q1 = *(const uint4*)(Sc + (size_t)p1.x * H);
        uint4 q2 = *(const uint4*)(Sc + (size_t)p2.x * H);
        uint4 q3 = *(const uint4*)(Sc + (size_t)p3.x * H);
        fma8(acc, q0, __int_as_float(p0.y));
        fma8(acc, q1, __int_as_float(p1.y));
        fma8(acc, q2, __int_as_float(p2.y));
        fma8(acc, q3, __int_as_float(p3.y));
    }
    for (; e < cnt; e++) {
        int2 p0 = cep[e];
        uint4 q0 = *(const uint4*)(Sc + (size_t)p0.x * H);
        fma8(acc, q0, __int_as_float(p0.y));
    }
    size_t idx = (size_t)v * H + l * 8;
    ushort4 o0, o1;
    o0.x = f2bf(acc[0]); o0.y = f2bf(acc[1]); o0.z = f2bf(acc[2]); o0.w = f2bf(acc[3]);
    o1.x = f2bf(acc[4]); o1.y = f2bf(acc[5]); o1.z = f2bf(acc[6]); o1.w = f2bf(acc[7]);
    *(ushort4*)&out[idx] = o0;
    *(ushort4*)&out[idx + 4] = o1;
}

// ---------------- Output head: coords = sup @ W_out + b_out ----------------

__global__ void head_kernel(const u16* __restrict__ A, const float* __restrict__ W,
                            const float* __restrict__ b, float* __restrict__ coords, int M) {
    int row = blockIdx.x * blockDim.x + threadIdx.x;
    if (row >= M) return;
    float a0 = b[0], a1 = b[1], a2 = b[2];
    const u16* Ar = A + (size_t)row * H;
    #pragma unroll
    for (int k8 = 0; k8 < H / 8; k8++) {
        short8 v = *(const short8*)(Ar + k8 * 8);
        #pragma unroll
        for (int j = 0; j < 8; j++) {
            float x = bf2f((u16)v[j]);
            int k = k8 * 8 + j;
            a0 += x * W[k * 3 + 0];
            a1 += x * W[k * 3 + 1];
            a2 += x * W[k * 3 + 2];
        }
    }
    coords[row * 3 + 0] = a0;
    coords[row * 3 + 1] = a1;
    coords[row * 3 + 2] = a2;
}

// ---------------- Launch ----------------

extern "C" void kernel_launch(void* const* d_in, const int* in_sizes, int n_in,
                              void* d_out, int out_size, void* d_ws, size_t ws_size,
                              hipStream_t stream) {
    const float* features = (const float*)d_in[0];
    const int*   edge_src = (const int*)d_in[1];
    const int*   edge_dst = (const int*)d_in[2];
    const float* edge_w   = (const float*)d_in[3];
    const float* Ws       = (const float*)d_in[4];
    const float* bs       = (const float*)d_in[5];
    const float* W_out    = (const float*)d_in[6];
    const float* b_out    = (const float*)d_in[7];

    const int N = in_sizes[0] / H;
    const int E = in_sizes[1];
    const int t1 = N / 3, t2 = 2 * N / 3;

    float* coords = (float*)d_out;
    float* feats  = coords + (size_t)N * 3;   // fp32 final feats (written at gc13 only)

    char* wptr = (char*)d_ws;
    u16* fbf  = (u16*)wptr;   wptr += (size_t)N * H * sizeof(u16);  // bf16 features
    u16* xb   = (u16*)wptr;   wptr += (size_t)N * H * sizeof(u16);  // x buffer
    u16* fA   = (u16*)wptr;   wptr += (size_t)N * H * sizeof(u16);  // feats ping
    u16* fB   = (u16*)wptr;   wptr += (size_t)N * H * sizeof(u16);  // feats pong
    u16* sup  = (u16*)wptr;   wptr += (size_t)N * H * sizeof(u16);  // head agg
    u16* Wf   = (u16*)wptr;   wptr += (size_t)NLAYER * LSTRIDE * sizeof(u16);
    int* counts2 = (int*)wptr; wptr += (size_t)N * 4 * sizeof(int);
    int* total   = (int*)wptr; wptr += 4;
    int* rbeg    = (int*)wptr; wptr += (size_t)N * sizeof(int);
    int* rcnt    = (int*)wptr; wptr += (size_t)N * sizeof(int);
    int* cursor  = (int*)wptr; wptr += (size_t)N * 4 * sizeof(int);
    int2* ce     = (int2*)wptr; wptr += (size_t)E * sizeof(int2);

    // --- build CSR (dst-indexed, scan-free, src-range-sorted rows) ---
    hipMemsetAsync(counts2, 0, ((size_t)N * 4 + 1) * sizeof(int), stream);  // counts2 + total
    hist2_kernel<<<(E + 255) / 256, 256, 0, stream>>>(edge_src, edge_dst, counts2, E, t1, t2);
    alloc2_kernel<<<(N + 255) / 256, 256, 0, stream>>>(counts2, rbeg, rcnt, cursor, total, N);
    scatter2_kernel<<<(E + 255) / 256, 256, 0, stream>>>(edge_src, edge_dst, edge_w,
                                                         cursor, ce, E, t1, t2);

    // --- weight split + fragment reorder + feature conversion ---
    int wtotal = NLAYER * HH;
    wprep_kernel<<<(wtotal + 255) / 256, 256, 0, stream>>>(Ws, Wf, wtotal);
    int c4 = N * H / 4;
    conv_kernel<<<(c4 + 255) / 256, 256, 0, stream>>>(features, fbf, c4);

    int lb = (N + 15) / 16;              // fused-layer blocks
    int VC = (N + 7) / 8;

    // L0: x0 = relu((adj@fbf) W0 + b0)            [gather fbf -> write xb]
    fused_layer<<<lb, 384, 0, stream>>>(fbf, rbeg, rcnt, ce, Wf + 0 * (size_t)LSTRIDE,
                                        bs + 0 * H, xb, nullptr, nullptr, 0, N);
    // L1: fA = (fbf + relu((adj@xb) W1 + b1))/2   [gather xb -> write fA, resid fbf RO]
    fused_layer<<<lb, 384, 0, stream>>>(xb, rbeg, rcnt, ce, Wf + 1 * (size_t)LSTRIDE,
                                        bs + 1 * H, fA, nullptr, fbf, 1, N);

    // blocks 2-6: ping-pong cur/nxt so gather input never aliases output
    u16* cur = fA;
    u16* nxt = fB;
    for (int i = 2; i < 12; i += 2) {
        fused_layer<<<lb, 384, 0, stream>>>(cur, rbeg, rcnt, ce, Wf + (size_t)i * LSTRIDE,
                                            bs + (size_t)i * H, xb, nullptr, nullptr, 0, N);
        fused_layer<<<lb, 384, 0, stream>>>(xb, rbeg, rcnt, ce, Wf + (size_t)(i+1) * LSTRIDE,
                                            bs + (size_t)(i+1) * H, nxt, nullptr, cur, 1, N);
        u16* t = cur; cur = nxt; nxt = t;
    }

    // gc13: gather cur -> write nxt (+ fp32 feats to d_out); resid cur RO
    fused_layer<<<lb, 384, 0, stream>>>(cur, rbeg, rcnt, ce, Wf + 12 * (size_t)LSTRIDE,
                                        bs + 12 * H, nxt, feats, cur, 2, N);

    // head: coords = (adj@nxt) W_out + b_out
    spmm_raw<<<VC, 192, 0, stream>>>(nxt, rbeg, rcnt, ce, sup, N);
    head_kernel<<<(N + 255) / 256, 256, 0, stream>>>(sup, W_out, b_out, coords, N);
}

// Round 3
// 719.052 us; speedup vs baseline: 1.8709x; 1.0482x over previous
//
#include <hip/hip_runtime.h>
#include <hip/hip_bf16.h>

#define H 192
#define HH (192*192)
#define NLAYER 13
#define LSTRIDE (2*HH)         // shorts per layer in fragment-ordered weight buffer
#define ASTRIDE 200            // A-tile row stride in shorts (400B, 16B-aligned)
#define VPB 32                 // vertices per fused block (2 MFMA row-tiles)

typedef unsigned short u16;
typedef unsigned int u32;

typedef __attribute__((ext_vector_type(8))) short short8;
typedef __attribute__((ext_vector_type(4))) float floatx4;

__device__ __forceinline__ u16 f2bf(float f) {
    u32 u = __float_as_uint(f);
    u32 r = (u + 0x7FFFu + ((u >> 16) & 1u)) >> 16;   // RNE
    return (u16)r;
}
__device__ __forceinline__ float bf2f(u16 h) {
    return __uint_as_float(((u32)h) << 16);
}

// ---------------- CSR construction (scan-free), src-range-sorted rows --------
// Edges within each dst row are bucketed by src range (3 ranges of ~N/3) so
// concurrently-running gather blocks sweep the same ~3.2MB of S rows.

__global__ void hist2_kernel(const int* __restrict__ src, const int* __restrict__ dst,
                             int* __restrict__ counts2, int E, int t1, int t2) {
    int e = blockIdx.x * blockDim.x + threadIdx.x;
    if (e < E) {
        int s = src[e];
        int r = (s >= t2) ? 2 : ((s >= t1) ? 1 : 0);
        atomicAdd(&counts2[dst[e] * 4 + r], 1);
    }
}

__global__ void alloc2_kernel(const int* __restrict__ counts2, int* __restrict__ rbeg,
                              int* __restrict__ rcnt, int* __restrict__ cursor,
                              int* __restrict__ total, int Nv) {
    int v = blockIdx.x * blockDim.x + threadIdx.x;
    if (v >= Nv) return;
    int c0 = counts2[v * 4 + 0];
    int c1 = counts2[v * 4 + 1];
    int c2 = counts2[v * 4 + 2];
    int tot = c0 + c1 + c2;
    int base = atomicAdd(total, tot);    // uniform-address: wave-coalesced by compiler
    rbeg[v] = base;
    rcnt[v] = tot;
    cursor[v * 4 + 0] = base;
    cursor[v * 4 + 1] = base + c0;
    cursor[v * 4 + 2] = base + c0 + c1;
}

__global__ void scatter2_kernel(const int* __restrict__ src, const int* __restrict__ dst,
                                const float* __restrict__ w, int* __restrict__ cursor,
                                int2* __restrict__ ce, int E, int t1, int t2) {
    int e = blockIdx.x * blockDim.x + threadIdx.x;
    if (e < E) {
        int s = src[e];
        int r = (s >= t2) ? 2 : ((s >= t1) ? 1 : 0);
        int p = atomicAdd(&cursor[dst[e] * 4 + r], 1);
        int2 pk; pk.x = s; pk.y = __float_as_int(w[e]);
        ce[p] = pk;
    }
}

// ---------------- Weight prep: fragment-ordered ----------------
// Wf[l][group][lane][j], group = ks*12 + nt. lane = quad*16 + col encodes
// B[n=nt*16+col][k=ks*32+quad*8+j]; hi at +0, lo at +512 within the group.

__global__ void wprep_kernel(const float* __restrict__ W, u16* __restrict__ Wf, int total) {
    int idx = blockIdx.x * blockDim.x + threadIdx.x;
    if (idx >= total) return;
    int l = idx / HH;
    int rem = idx - l * HH;
    int k = rem / H;
    int n = rem - k * H;
    float v = W[idx];
    u16 hi = f2bf(v);
    u16 lo = f2bf(v - bf2f(hi));
    int ks = k >> 5, quad = (k >> 3) & 3, j = k & 7;
    int nt = n >> 4, col = n & 15;
    int lane = quad * 16 + col;
    size_t base = (size_t)l * LSTRIDE + (size_t)(ks * 12 + nt) * 1024 + lane * 8 + j;
    Wf[base] = hi;
    Wf[base + 512] = lo;
}

// ---------------- features fp32 -> bf16 ----------------

__global__ void conv_kernel(const float* __restrict__ in, u16* __restrict__ out, int total4) {
    int idx = blockIdx.x * blockDim.x + threadIdx.x;
    if (idx >= total4) return;
    float4 v = ((const float4*)in)[idx];
    ushort4 p;
    p.x = f2bf(v.x); p.y = f2bf(v.y); p.z = f2bf(v.z); p.w = f2bf(v.w);
    ((ushort4*)out)[idx] = p;
}

// ---------------- common fma helper ----------------

__device__ __forceinline__ void fma8(float* acc, uint4 q, float w) {
    u32 u[4] = {q.x, q.y, q.z, q.w};
    #pragma unroll
    for (int i = 0; i < 4; i++) {
        float lo = __uint_as_float(u[i] << 16);
        float hi = __uint_as_float(u[i] & 0xFFFF0000u);
        acc[2*i]     += w * lo;
        acc[2*i + 1] += w * hi;
    }
}

// ---------------- Fused layer: agg = adj @ S ; out = epilogue(agg @ W + b) ---
// RACE RULE: S (gather input) must NEVER alias out_bf/out_f. resid_bf may
// alias S (read-only).
// Block = 384 threads = 32 dst vertices x 12 lanes (lane owns 16 cols, 32B).
// Phase 1: per edge, 2 uint4 loads; 4-edge unroll (8 row-loads in flight).
//   Edges src-range-sorted for XCD-L2 temporal locality across blocks.
// Phase 2: 6 waves; wave w does n-tiles {w, w+6} for BOTH 16-row tiles;
//   B-frags loaded once per ks and reused across the 2 row tiles -> Wf L2
//   traffic halved vs 16-row blocks. A via ds_read_b128 from LDS.
// mode 0: out_bf = bf16(relu(C+b)); mode 1: f=(resid+relu(C+b))*0.5 -> out_bf;
// mode 2: mode 1 + out_f = f (fp32).

__global__ __launch_bounds__(384) void fused_layer(
    const u16* __restrict__ S, const int* __restrict__ rbeg, const int* __restrict__ rcnt,
    const int2* __restrict__ ce, const u16* __restrict__ Wf, const float* __restrict__ bias,
    u16* __restrict__ out_bf, float* __restrict__ out_f, const u16* __restrict__ resid_bf,
    int mode, int M)
{
    __shared__ u16 shA[VPB * ASTRIDE];   // 12.8 KB A-tile (32 rows)
    int tid = threadIdx.x;
    int vg = tid / 12;                   // vertex 0..31
    int l  = tid - vg * 12;              // lane in vertex, owns cols l*16..l*16+15
    int v = blockIdx.x * VPB + vg;

    float acc[16] = {};
    if (v < M) {
        int beg = rbeg[v], cnt = rcnt[v];
        const int2* cep = ce + beg;
        const u16* Sc = S + l * 16;
        int e = 0;
        for (; e + 3 < cnt; e += 4) {
            int2 p0 = cep[e], p1 = cep[e + 1], p2 = cep[e + 2], p3 = cep[e + 3];
            const u16* r0 = Sc + (size_t)p0.x * H;
            const u16* r1 = Sc + (size_t)p1.x * H;
            const u16* r2 = Sc + (size_t)p2.x * H;
            const u16* r3 = Sc + (size_t)p3.x * H;
            uint4 q0a = *(const uint4*)r0, q0b = *(const uint4*)(r0 + 8);
            uint4 q1a = *(const uint4*)r1, q1b = *(const uint4*)(r1 + 8);
            uint4 q2a = *(const uint4*)r2, q2b = *(const uint4*)(r2 + 8);
            uint4 q3a = *(const uint4*)r3, q3b = *(const uint4*)(r3 + 8);
            float w0 = __int_as_float(p0.y), w1 = __int_as_float(p1.y);
            float w2 = __int_as_float(p2.y), w3 = __int_as_float(p3.y);
            fma8(acc, q0a, w0); fma8(acc + 8, q0b, w0);
            fma8(acc, q1a, w1); fma8(acc + 8, q1b, w1);
            fma8(acc, q2a, w2); fma8(acc + 8, q2b, w2);
            fma8(acc, q3a, w3); fma8(acc + 8, q3b, w3);
        }
        for (; e < cnt; e++) {
            int2 p0 = cep[e];
            const u16* r0 = Sc + (size_t)p0.x * H;
            uint4 qa = *(const uint4*)r0, qb = *(const uint4*)(r0 + 8);
            float w0 = __int_as_float(p0.y);
            fma8(acc, qa, w0); fma8(acc + 8, qb, w0);
        }
    }
    {
        uint4 pa, pb;
        pa.x = (u32)f2bf(acc[0])  | ((u32)f2bf(acc[1])  << 16);
        pa.y = (u32)f2bf(acc[2])  | ((u32)f2bf(acc[3])  << 16);
        pa.z = (u32)f2bf(acc[4])  | ((u32)f2bf(acc[5])  << 16);
        pa.w = (u32)f2bf(acc[6])  | ((u32)f2bf(acc[7])  << 16);
        pb.x = (u32)f2bf(acc[8])  | ((u32)f2bf(acc[9])  << 16);
        pb.y = (u32)f2bf(acc[10]) | ((u32)f2bf(acc[11]) << 16);
        pb.z = (u32)f2bf(acc[12]) | ((u32)f2bf(acc[13]) << 16);
        pb.w = (u32)f2bf(acc[14]) | ((u32)f2bf(acc[15]) << 16);
        *(uint4*)&shA[vg * ASTRIDE + l * 16] = pa;
        *(uint4*)&shA[vg * ASTRIDE + l * 16 + 8] = pb;
    }
    __syncthreads();

    // ---- phase 2: MFMA (6 waves x 2 n-tiles x 2 row-tiles, B reused) ----
    int wave = tid >> 6, lane = tid & 63;
    int col = lane & 15, quad = lane >> 4;

    short8 a0[6], a1[6];
    {
        const u16* Ar0 = &shA[col * ASTRIDE + quad * 8];
        const u16* Ar1 = &shA[(16 + col) * ASTRIDE + quad * 8];
        #pragma unroll
        for (int ks = 0; ks < 6; ks++) {
            a0[ks] = *(const short8*)(Ar0 + ks * 32);
            a1[ks] = *(const short8*)(Ar1 + ks * 32);
        }
    }

    int nt0 = wave, nt1 = wave + 6;
    floatx4 c00 = {0.f, 0.f, 0.f, 0.f}, c01 = {0.f, 0.f, 0.f, 0.f};
    floatx4 c10 = {0.f, 0.f, 0.f, 0.f}, c11 = {0.f, 0.f, 0.f, 0.f};
    #pragma unroll
    for (int ks = 0; ks < 6; ks++) {
        const u16* g0 = Wf + (size_t)(ks * 12 + nt0) * 1024 + lane * 8;
        const u16* g1 = Wf + (size_t)(ks * 12 + nt1) * 1024 + lane * 8;
        short8 bh0 = *(const short8*)g0;
        short8 bl0 = *(const short8*)(g0 + 512);
        short8 bh1 = *(const short8*)g1;
        short8 bl1 = *(const short8*)(g1 + 512);
        c00 = __builtin_amdgcn_mfma_f32_16x16x32_bf16(a0[ks], bh0, c00, 0, 0, 0);
        c00 = __builtin_amdgcn_mfma_f32_16x16x32_bf16(a0[ks], bl0, c00, 0, 0, 0);
        c10 = __builtin_amdgcn_mfma_f32_16x16x32_bf16(a1[ks], bh0, c10, 0, 0, 0);
        c10 = __builtin_amdgcn_mfma_f32_16x16x32_bf16(a1[ks], bl0, c10, 0, 0, 0);
        c01 = __builtin_amdgcn_mfma_f32_16x16x32_bf16(a0[ks], bh1, c01, 0, 0, 0);
        c01 = __builtin_amdgcn_mfma_f32_16x16x32_bf16(a0[ks], bl1, c01, 0, 0, 0);
        c11 = __builtin_amdgcn_mfma_f32_16x16x32_bf16(a1[ks], bh1, c11, 0, 0, 0);
        c11 = __builtin_amdgcn_mfma_f32_16x16x32_bf16(a1[ks], bl1, c11, 0, 0, 0);
    }

    // ---- epilogue: C layout col=lane&15, row=quad*4+r ----
    int rm = blockIdx.x * VPB;
    #pragma unroll
    for (int tile = 0; tile < 2; tile++) {
        int rbase = rm + tile * 16;
        #pragma unroll
        for (int half = 0; half < 2; half++) {
            int nt = half ? nt1 : nt0;
            floatx4 cc = tile ? (half ? c11 : c10) : (half ? c01 : c00);
            int n = nt * 16 + col;
            float b = bias[n];
            #pragma unroll
            for (int r = 0; r < 4; r++) {
                int row = rbase + quad * 4 + r;
                if (row < M) {
                    float z = fmaxf(cc[r] + b, 0.f);
                    size_t o = (size_t)row * H + n;
                    if (mode >= 1) {
                        float f = (bf2f(resid_bf[o]) + z) * 0.5f;
                        out_bf[o] = f2bf(f);
                        if (mode == 2) out_f[o] = f;
                    } else {
                        out_bf[o] = f2bf(z);
                    }
                }
            }
        }
    }
}

// ---------------- head gather: sup = adj @ feats_bf ----------------

__global__ __launch_bounds__(192) void spmm_raw(
    const u16* __restrict__ S, const int* __restrict__ rbeg, const int* __restrict__ rcnt,
    const int2* __restrict__ ce, u16* __restrict__ out, int Nv)
{
    int tid = threadIdx.x;
    int g = tid / 24;
    int l = tid - g * 24;
    int v = blockIdx.x * 8 + g;
    if (v >= Nv) return;
    int beg = rbeg[v], cnt = rcnt[v];
    const int2* cep = ce + beg;
    const u16* Sc = S + l * 8;
    float acc[8] = {};
    int e = 0;
    for (; e + 3 < cnt; e += 4) {
        int2 p0 = cep[e], p1 = cep[e + 1], p2 = cep[e + 2], p3 = cep[e + 3];
        uint4 q0 = *(const uint4*)(Sc + (size_t)p0.x * H);
        uint4 q1 = *(const uint4*)(Sc + (size_t)p1.x * H);
        uint4 q2 = *(const uint4*)(Sc + (size_t)p2.x * H);
        uint4 q3 = *(const uint4*)(Sc + (size_t)p3.x * H);
        fma8(acc, q0, __int_as_float(p0.y));
        fma8(acc, q1, __int_as_float(p1.y));
        fma8(acc, q2, __int_as_float(p2.y));
        fma8(acc, q3, __int_as_float(p3.y));
    }
    for (; e < cnt; e++) {
        int2 p0 = cep[e];
        uint4 q0 = *(const uint4*)(Sc + (size_t)p0.x * H);
        fma8(acc, q0, __int_as_float(p0.y));
    }
    size_t idx = (size_t)v * H + l * 8;
    ushort4 o0, o1;
    o0.x = f2bf(acc[0]); o0.y = f2bf(acc[1]); o0.z = f2bf(acc[2]); o0.w = f2bf(acc[3]);
    o1.x = f2bf(acc[4]); o1.y = f2bf(acc[5]); o1.z = f2bf(acc[6]); o1.w = f2bf(acc[7]);
    *(ushort4*)&out[idx] = o0;
    *(ushort4*)&out[idx + 4] = o1;
}

// ---------------- Output head: coords = sup @ W_out + b_out ----------------

__global__ void head_kernel(const u16* __restrict__ A, const float* __restrict__ W,
                            const float* __restrict__ b, float* __restrict__ coords, int M) {
    int row = blockIdx.x * blockDim.x + threadIdx.x;
    if (row >= M) return;
    float a0 = b[0], a1 = b[1], a2 = b[2];
    const u16* Ar = A + (size_t)row * H;
    #pragma unroll
    for (int k8 = 0; k8 < H / 8; k8++) {
        short8 v = *(const short8*)(Ar + k8 * 8);
        #pragma unroll
        for (int j = 0; j < 8; j++) {
            float x = bf2f((u16)v[j]);
            int k = k8 * 8 + j;
            a0 += x * W[k * 3 + 0];
            a1 += x * W[k * 3 + 1];
            a2 += x * W[k * 3 + 2];
        }
    }
    coords[row * 3 + 0] = a0;
    coords[row * 3 + 1] = a1;
    coords[row * 3 + 2] = a2;
}

// ---------------- Launch ----------------

extern "C" void kernel_launch(void* const* d_in, const int* in_sizes, int n_in,
                              void* d_out, int out_size, void* d_ws, size_t ws_size,
                              hipStream_t stream) {
    const float* features = (const float*)d_in[0];
    const int*   edge_src = (const int*)d_in[1];
    const int*   edge_dst = (const int*)d_in[2];
    const float* edge_w   = (const float*)d_in[3];
    const float* Ws       = (const float*)d_in[4];
    const float* bs       = (const float*)d_in[5];
    const float* W_out    = (const float*)d_in[6];
    const float* b_out    = (const float*)d_in[7];

    const int N = in_sizes[0] / H;
    const int E = in_sizes[1];
    const int t1 = N / 3, t2 = 2 * N / 3;

    float* coords = (float*)d_out;
    float* feats  = coords + (size_t)N * 3;   // fp32 final feats (written at gc13 only)

    char* wptr = (char*)d_ws;
    u16* fbf  = (u16*)wptr;   wptr += (size_t)N * H * sizeof(u16);  // bf16 features
    u16* xb   = (u16*)wptr;   wptr += (size_t)N * H * sizeof(u16);  // x buffer
    u16* fA   = (u16*)wptr;   wptr += (size_t)N * H * sizeof(u16);  // feats ping
    u16* fB   = (u16*)wptr;   wptr += (size_t)N * H * sizeof(u16);  // feats pong
    u16* sup  = (u16*)wptr;   wptr += (size_t)N * H * sizeof(u16);  // head agg
    u16* Wf   = (u16*)wptr;   wptr += (size_t)NLAYER * LSTRIDE * sizeof(u16);
    int* counts2 = (int*)wptr; wptr += (size_t)N * 4 * sizeof(int);
    int* total   = (int*)wptr; wptr += 4;
    int* rbeg    = (int*)wptr; wptr += (size_t)N * sizeof(int);
    int* rcnt    = (int*)wptr; wptr += (size_t)N * sizeof(int);
    int* cursor  = (int*)wptr; wptr += (size_t)N * 4 * sizeof(int);
    int2* ce     = (int2*)wptr; wptr += (size_t)E * sizeof(int2);

    // --- build CSR (dst-indexed, scan-free, src-range-sorted rows) ---
    hipMemsetAsync(counts2, 0, ((size_t)N * 4 + 1) * sizeof(int), stream);  // counts2 + total
    hist2_kernel<<<(E + 255) / 256, 256, 0, stream>>>(edge_src, edge_dst, counts2, E, t1, t2);
    alloc2_kernel<<<(N + 255) / 256, 256, 0, stream>>>(counts2, rbeg, rcnt, cursor, total, N);
    scatter2_kernel<<<(E + 255) / 256, 256, 0, stream>>>(edge_src, edge_dst, edge_w,
                                                         cursor, ce, E, t1, t2);

    // --- weight split + fragment reorder + feature conversion ---
    int wtotal = NLAYER * HH;
    wprep_kernel<<<(wtotal + 255) / 256, 256, 0, stream>>>(Ws, Wf, wtotal);
    int c4 = N * H / 4;
    conv_kernel<<<(c4 + 255) / 256, 256, 0, stream>>>(features, fbf, c4);

    int lb = (N + VPB - 1) / VPB;        // fused-layer blocks (32 rows each)
    int VC = (N + 7) / 8;

    // L0: x0 = relu((adj@fbf) W0 + b0)            [gather fbf -> write xb]
    fused_layer<<<lb, 384, 0, stream>>>(fbf, rbeg, rcnt, ce, Wf + 0 * (size_t)LSTRIDE,
                                        bs + 0 * H, xb, nullptr, nullptr, 0, N);
    // L1: fA = (fbf + relu((adj@xb) W1 + b1))/2   [gather xb -> write fA, resid fbf RO]
    fused_layer<<<lb, 384, 0, stream>>>(xb, rbeg, rcnt, ce, Wf + 1 * (size_t)LSTRIDE,
                                        bs + 1 * H, fA, nullptr, fbf, 1, N);

    // blocks 2-6: ping-pong cur/nxt so gather input never aliases output
    u16* cur = fA;
    u16* nxt = fB;
    for (int i = 2; i < 12; i += 2) {
        fused_layer<<<lb, 384, 0, stream>>>(cur, rbeg, rcnt, ce, Wf + (size_t)i * LSTRIDE,
                                            bs + (size_t)i * H, xb, nullptr, nullptr, 0, N);
        fused_layer<<<lb, 384, 0, stream>>>(xb, rbeg, rcnt, ce, Wf + (size_t)(i+1) * LSTRIDE,
                                            bs + (size_t)(i+1) * H, nxt, nullptr, cur, 1, N);
        u16* t = cur; cur = nxt; nxt = t;
    }

    // gc13: gather cur -> write nxt (+ fp32 feats to d_out); resid cur RO
    fused_layer<<<lb, 384, 0, stream>>>(cur, rbeg, rcnt, ce, Wf + 12 * (size_t)LSTRIDE,
                                        bs + 12 * H, nxt, feats, cur, 2, N);

    // head: coords = (adj@nxt) W_out + b_out
    spmm_raw<<<VC, 192, 0, stream>>>(nxt, rbeg, rcnt, ce, sup, N);
    head_kernel<<<(N + 255) / 256, 256, 0, stream>>>(sup, W_out, b_out, coords, N);
}